// Round 1
// baseline (2324.255 us; speedup 1.0000x reference)
//
#include <hip/hip_runtime.h>
#include <stdint.h>

#define NE    8
#define HID   2048
#define INTER 7168
#define TTOK  8192

typedef __bf16 bf16;
typedef bf16 bf16x4 __attribute__((ext_vector_type(4)));
typedef bf16 bf16x8 __attribute__((ext_vector_type(8)));
typedef float f32x4 __attribute__((ext_vector_type(4)));

__device__ __forceinline__ void glds16(const void* g, void* l) {
  __builtin_amdgcn_global_load_lds((__attribute__((address_space(1))) void*)g,
                                   (__attribute__((address_space(3))) void*)l, 16, 0, 0);
}

// ---------------- fp32 -> bf16 conversion (vectorized, grid-stride) ----------------
__global__ void cvt_f32_bf16(const float* __restrict__ src, bf16* __restrict__ dst, long n) {
  long i = (long)blockIdx.x * blockDim.x + threadIdx.x;
  long stride = (long)gridDim.x * blockDim.x;
  for (long j = i * 4; j < n; j += stride * 4) {
    float4 v = *(const float4*)(src + j);
    bf16x4 o = {(bf16)v.x, (bf16)v.y, (bf16)v.z, (bf16)v.w};
    *(bf16x4*)(dst + j) = o;
  }
}

// ---------------- router: one wave per token, fp32 ----------------
__global__ void router_kernel(const float* __restrict__ x, const float* __restrict__ gw,
                              int* __restrict__ topk_e, float* __restrict__ topk_w) {
  const int wid = threadIdx.x >> 6, lane = threadIdx.x & 63;
  const int t = blockIdx.x * 4 + wid;
  if (t >= TTOK) return;
  const float* xr = x + (size_t)t * HID;
  float xv[32];
#pragma unroll
  for (int i = 0; i < 32; ++i) xv[i] = xr[lane + 64 * i];
  float lg[NE];
#pragma unroll
  for (int e = 0; e < NE; ++e) {
    const float* g = gw + e * HID;
    float s = 0.f;
#pragma unroll
    for (int i = 0; i < 32; ++i) s += xv[i] * g[lane + 64 * i];
#pragma unroll
    for (int off = 32; off; off >>= 1) s += __shfl_down(s, off);
    lg[e] = s; // valid on lane 0
  }
  if (lane == 0) {
    int i1 = 0;
#pragma unroll
    for (int e = 1; e < NE; ++e) if (lg[e] > lg[i1]) i1 = e;
    int i2 = (i1 == 0) ? 1 : 0;
#pragma unroll
    for (int e = 0; e < NE; ++e) if (e != i2 && e != i1 && lg[e] > lg[i2]) i2 = e;
    // renormalized top-2 softmax weights: full softmax denominator cancels
    float r = __expf(lg[i2] - lg[i1]); // <= 1
    float wa = 1.f / (1.f + r);
    topk_e[2 * t] = i1; topk_e[2 * t + 1] = i2;
    topk_w[2 * t] = wa; topk_w[2 * t + 1] = 1.f - wa;
  }
}

// ---------------- gather per-expert token lists ----------------
__global__ void gather_kernel(const int* __restrict__ topk_e, const float* __restrict__ topk_w,
                              int* __restrict__ cnt, int* __restrict__ ltok, float* __restrict__ lw) {
  const int t = blockIdx.x * blockDim.x + threadIdx.x;
  if (t >= TTOK) return;
#pragma unroll
  for (int j = 0; j < 2; ++j) {
    int e = topk_e[2 * t + j];
    int s = atomicAdd(&cnt[e], 1);
    ltok[e * TTOK + s] = t;
    lw[e * TTOK + s] = topk_w[2 * t + j];
  }
}

__global__ void prefix_kernel(const int* __restrict__ cnt, int* __restrict__ base) {
  if (threadIdx.x == 0 && blockIdx.x == 0) {
    int b = 0;
    for (int e = 0; e < NE; ++e) { base[e] = b; b += cnt[e]; }
  }
}

// ---------------- pass1: h = silu(x w1^T) * (x w3^T), gathered rows ----------------
// 128x128 tile, BK=32, 4 waves (2x2), each wave 4x4 frags of 16x16x32 bf16.
__launch_bounds__(256, 2)
__global__ void pass1_kernel(const bf16* __restrict__ xb, const bf16* __restrict__ w1b,
                             const bf16* __restrict__ w3b, bf16* __restrict__ hbuf,
                             const int* __restrict__ cnt, const int* __restrict__ base,
                             const int* __restrict__ ltok) {
  const int e = blockIdx.z;
  const int c = cnt[e];
  const int tm = blockIdx.y;
  if (tm * 128 >= c) return;
  const int tn = blockIdx.x;
  __shared__ __align__(16) bf16 lA[128 * 32];
  __shared__ __align__(16) bf16 lB1[128 * 32];
  __shared__ __align__(16) bf16 lB3[128 * 32];
  const int tid = threadIdx.x;
  // staging: chunk c0=tid, c1=tid+256; row = chunk>>2 (64B rows), sub = (chunk&3)*16B
  const int r0 = tid >> 2, r1 = r0 + 64;
  const int sub = (tid & 3) * 16;
  int s0 = tm * 128 + r0; if (s0 >= c) s0 = c - 1;
  int s1 = tm * 128 + r1; if (s1 >= c) s1 = c - 1;
  const char* gA0 = (const char*)(xb + (size_t)ltok[e * TTOK + s0] * HID) + sub;
  const char* gA1 = (const char*)(xb + (size_t)ltok[e * TTOK + s1] * HID) + sub;
  const char* gB1r0 = (const char*)(w1b + ((size_t)e * INTER + tn * 128 + r0) * HID) + sub;
  const char* gB1r1 = (const char*)(w1b + ((size_t)e * INTER + tn * 128 + r1) * HID) + sub;
  const char* gB3r0 = (const char*)(w3b + ((size_t)e * INTER + tn * 128 + r0) * HID) + sub;
  const char* gB3r1 = (const char*)(w3b + ((size_t)e * INTER + tn * 128 + r1) * HID) + sub;
  bf16* lA0 = &lA[tid * 8];  bf16* lA1 = &lA[(tid + 256) * 8];
  bf16* lB1p0 = &lB1[tid * 8]; bf16* lB1p1 = &lB1[(tid + 256) * 8];
  bf16* lB3p0 = &lB3[tid * 8]; bf16* lB3p1 = &lB3[(tid + 256) * 8];

  const int lane = tid & 63;
  const int wid = tid >> 6;
  const int wm = wid >> 1, wn = wid & 1;
  const int ln15 = lane & 15, kq = lane >> 4;

  f32x4 ag[4][4], au[4][4];
#pragma unroll
  for (int m = 0; m < 4; ++m)
#pragma unroll
    for (int n = 0; n < 4; ++n) {
      ag[m][n] = (f32x4){0.f, 0.f, 0.f, 0.f};
      au[m][n] = (f32x4){0.f, 0.f, 0.f, 0.f};
    }

  for (int kt = 0; kt < HID / 32; ++kt) {
    const int kb = kt * 64; // bytes along K
    __syncthreads();
    glds16(gA0 + kb, lA0);   glds16(gA1 + kb, lA1);
    glds16(gB1r0 + kb, lB1p0); glds16(gB1r1 + kb, lB1p1);
    glds16(gB3r0 + kb, lB3p0); glds16(gB3r1 + kb, lB3p1);
    __syncthreads();
    bf16x8 af[4];
#pragma unroll
    for (int m = 0; m < 4; ++m)
      af[m] = *(const bf16x8*)&lA[(wm * 64 + m * 16 + ln15) * 32 + kq * 8];
#pragma unroll
    for (int n = 0; n < 4; ++n) {
      bf16x8 b1 = *(const bf16x8*)&lB1[(wn * 64 + n * 16 + ln15) * 32 + kq * 8];
      bf16x8 b3 = *(const bf16x8*)&lB3[(wn * 64 + n * 16 + ln15) * 32 + kq * 8];
#pragma unroll
      for (int m = 0; m < 4; ++m) {
        ag[m][n] = __builtin_amdgcn_mfma_f32_16x16x32_bf16(af[m], b1, ag[m][n], 0, 0, 0);
        au[m][n] = __builtin_amdgcn_mfma_f32_16x16x32_bf16(af[m], b3, au[m][n], 0, 0, 0);
      }
    }
  }

  const int be = base[e];
#pragma unroll
  for (int m = 0; m < 4; ++m) {
#pragma unroll
    for (int j = 0; j < 4; ++j) {
      const int slot = tm * 128 + wm * 64 + m * 16 + kq * 4 + j; // C/D: row=(lane>>4)*4+reg
      if (slot < c) {
        bf16* hrow = hbuf + (size_t)(be + slot) * INTER + tn * 128;
#pragma unroll
        for (int n = 0; n < 4; ++n) {
          const int col = wn * 64 + n * 16 + ln15; // C/D: col=lane&15
          const float g = ag[m][n][j];
          const float u = au[m][n][j];
          const float hv = g / (1.f + __expf(-g)) * u; // silu(g)*u
          hrow[col] = (bf16)hv;
        }
      }
    }
  }
}

// ---------------- pass2: out[t,:] += w * (h w2^T), scatter-add ----------------
__launch_bounds__(256, 2)
__global__ void pass2_kernel(const bf16* __restrict__ hbuf, const bf16* __restrict__ w2b,
                             float* __restrict__ out, const int* __restrict__ cnt,
                             const int* __restrict__ base, const int* __restrict__ ltok,
                             const float* __restrict__ lw) {
  const int e = blockIdx.z;
  const int c = cnt[e];
  const int tm = blockIdx.y;
  if (tm * 128 >= c) return;
  const int tn = blockIdx.x;
  __shared__ __align__(16) bf16 lA[128 * 32];
  __shared__ __align__(16) bf16 lB[128 * 32];
  const int tid = threadIdx.x;
  const int r0 = tid >> 2, r1 = r0 + 64;
  const int sub = (tid & 3) * 16;
  const int be = base[e];
  int s0 = tm * 128 + r0; if (s0 >= c) s0 = c - 1;
  int s1 = tm * 128 + r1; if (s1 >= c) s1 = c - 1;
  const char* gA0 = (const char*)(hbuf + (size_t)(be + s0) * INTER) + sub;
  const char* gA1 = (const char*)(hbuf + (size_t)(be + s1) * INTER) + sub;
  const char* gB0 = (const char*)(w2b + ((size_t)e * HID + tn * 128 + r0) * INTER) + sub;
  const char* gB1 = (const char*)(w2b + ((size_t)e * HID + tn * 128 + r1) * INTER) + sub;
  bf16* lA0 = &lA[tid * 8]; bf16* lA1 = &lA[(tid + 256) * 8];
  bf16* lB0 = &lB[tid * 8]; bf16* lB1p = &lB[(tid + 256) * 8];

  const int lane = tid & 63;
  const int wid = tid >> 6;
  const int wm = wid >> 1, wn = wid & 1;
  const int ln15 = lane & 15, kq = lane >> 4;

  f32x4 acc[4][4];
#pragma unroll
  for (int m = 0; m < 4; ++m)
#pragma unroll
    for (int n = 0; n < 4; ++n) acc[m][n] = (f32x4){0.f, 0.f, 0.f, 0.f};

  for (int kt = 0; kt < INTER / 32; ++kt) {
    const int kb = kt * 64;
    __syncthreads();
    glds16(gA0 + kb, lA0); glds16(gA1 + kb, lA1);
    glds16(gB0 + kb, lB0); glds16(gB1 + kb, lB1p);
    __syncthreads();
    bf16x8 af[4];
#pragma unroll
    for (int m = 0; m < 4; ++m)
      af[m] = *(const bf16x8*)&lA[(wm * 64 + m * 16 + ln15) * 32 + kq * 8];
#pragma unroll
    for (int n = 0; n < 4; ++n) {
      bf16x8 bf_ = *(const bf16x8*)&lB[(wn * 64 + n * 16 + ln15) * 32 + kq * 8];
#pragma unroll
      for (int m = 0; m < 4; ++m)
        acc[m][n] = __builtin_amdgcn_mfma_f32_16x16x32_bf16(af[m], bf_, acc[m][n], 0, 0, 0);
    }
  }

#pragma unroll
  for (int m = 0; m < 4; ++m) {
#pragma unroll
    for (int j = 0; j < 4; ++j) {
      const int slot = tm * 128 + wm * 64 + m * 16 + kq * 4 + j;
      if (slot < c) {
        const int t = ltok[e * TTOK + slot];
        const float wt = lw[e * TTOK + slot];
        float* orow = out + (size_t)t * HID + tn * 128;
#pragma unroll
        for (int n = 0; n < 4; ++n) {
          const int col = wn * 64 + n * 16 + ln15;
          atomicAdd(orow + col, wt * acc[m][n][j]);
        }
      }
    }
  }
}

extern "C" void kernel_launch(void* const* d_in, const int* in_sizes, int n_in,
                              void* d_out, int out_size, void* d_ws, size_t ws_size,
                              hipStream_t stream) {
  const float* x  = (const float*)d_in[0];
  const float* gw = (const float*)d_in[1];
  const float* w1 = (const float*)d_in[2];
  const float* w3 = (const float*)d_in[3];
  const float* w2 = (const float*)d_in[4];
  float* out = (float*)d_out;

  char* ws = (char*)d_ws;
  size_t off = 0;
  auto take = [&](size_t bytes) -> char* {
    char* p = ws + off;
    off += (bytes + 255) & ~(size_t)255;
    return p;
  };
  bf16* xb    = (bf16*)take((size_t)TTOK * HID * 2);          // 32 MB
  bf16* w1b   = (bf16*)take((size_t)NE * INTER * HID * 2);    // 235 MB
  bf16* w3b   = (bf16*)take((size_t)NE * INTER * HID * 2);    // 235 MB
  bf16* w2b   = (bf16*)take((size_t)NE * HID * INTER * 2);    // 235 MB
  bf16* hbuf  = (bf16*)take((size_t)TTOK * 2 * INTER * 2);    // 235 MB (16384 pair rows)
  int*   topk_e = (int*)take(TTOK * 2 * 4);
  float* topk_w = (float*)take(TTOK * 2 * 4);
  int*   ltok   = (int*)take(NE * TTOK * 4);
  float* lwgt   = (float*)take(NE * TTOK * 4);
  int*   cntp   = (int*)take(64);
  int*   basep  = (int*)take(64);
  if (off > ws_size) return; // insufficient workspace -> visible failure

  hipMemsetAsync(d_out, 0, (size_t)out_size * 4, stream);
  hipMemsetAsync(cntp, 0, 64, stream);

  cvt_f32_bf16<<<2048, 256, 0, stream>>>(x,  xb,  (long)TTOK * HID);
  cvt_f32_bf16<<<4096, 256, 0, stream>>>(w1, w1b, (long)NE * INTER * HID);
  cvt_f32_bf16<<<4096, 256, 0, stream>>>(w3, w3b, (long)NE * INTER * HID);
  cvt_f32_bf16<<<4096, 256, 0, stream>>>(w2, w2b, (long)NE * HID * INTER);

  router_kernel<<<TTOK / 4, 256, 0, stream>>>(x, gw, topk_e, topk_w);
  gather_kernel<<<TTOK / 256, 256, 0, stream>>>(topk_e, topk_w, cntp, ltok, lwgt);
  prefix_kernel<<<1, 64, 0, stream>>>(cntp, basep);

  pass1_kernel<<<dim3(INTER / 128, TTOK / 128, NE), 256, 0, stream>>>(
      xb, w1b, w3b, hbuf, cntp, basep, ltok);
  pass2_kernel<<<dim3(HID / 128, TTOK / 128, NE), 256, 0, stream>>>(
      hbuf, w2b, out, cntp, basep, ltok, lwgt);
}

// Round 2
// 2291.646 us; speedup vs baseline: 1.0142x; 1.0142x over previous
//
#include <hip/hip_runtime.h>
#include <stdint.h>

#define NE    8
#define HID   2048
#define INTER 7168
#define TTOK  8192
#define NT1   (HID / 64)    // 32 K-tiles for pass1
#define NT2   (INTER / 64)  // 112 K-tiles for pass2

typedef __bf16 bf16;
typedef bf16 bf16x4 __attribute__((ext_vector_type(4)));
typedef bf16 bf16x8 __attribute__((ext_vector_type(8)));
typedef float f32x4 __attribute__((ext_vector_type(4)));

__device__ __forceinline__ void glds16(const void* g, void* l) {
  __builtin_amdgcn_global_load_lds((__attribute__((address_space(1))) void*)g,
                                   (__attribute__((address_space(3))) void*)l, 16, 0, 0);
}

// ---------------- fp32 -> bf16 conversion ----------------
__global__ void cvt_f32_bf16(const float* __restrict__ src, bf16* __restrict__ dst, long n) {
  long i = (long)blockIdx.x * blockDim.x + threadIdx.x;
  long stride = (long)gridDim.x * blockDim.x;
  for (long j = i * 4; j < n; j += stride * 4) {
    float4 v = *(const float4*)(src + j);
    bf16x4 o = {(bf16)v.x, (bf16)v.y, (bf16)v.z, (bf16)v.w};
    *(bf16x4*)(dst + j) = o;
  }
}

// ---------------- router ----------------
__global__ void router_kernel(const float* __restrict__ x, const float* __restrict__ gw,
                              int* __restrict__ topk_e, float* __restrict__ topk_w) {
  const int wid = threadIdx.x >> 6, lane = threadIdx.x & 63;
  const int t = blockIdx.x * 4 + wid;
  if (t >= TTOK) return;
  const float* xr = x + (size_t)t * HID;
  float xv[32];
#pragma unroll
  for (int i = 0; i < 32; ++i) xv[i] = xr[lane + 64 * i];
  float lg[NE];
#pragma unroll
  for (int e = 0; e < NE; ++e) {
    const float* g = gw + e * HID;
    float s = 0.f;
#pragma unroll
    for (int i = 0; i < 32; ++i) s += xv[i] * g[lane + 64 * i];
#pragma unroll
    for (int off = 32; off; off >>= 1) s += __shfl_down(s, off);
    lg[e] = s;
  }
  if (lane == 0) {
    int i1 = 0;
#pragma unroll
    for (int e = 1; e < NE; ++e) if (lg[e] > lg[i1]) i1 = e;
    int i2 = (i1 == 0) ? 1 : 0;
#pragma unroll
    for (int e = 0; e < NE; ++e) if (e != i2 && e != i1 && lg[e] > lg[i2]) i2 = e;
    float r = __expf(lg[i2] - lg[i1]);
    float wa = 1.f / (1.f + r);
    topk_e[2 * t] = i1; topk_e[2 * t + 1] = i2;
    topk_w[2 * t] = wa; topk_w[2 * t + 1] = 1.f - wa;
  }
}

__global__ void gather_kernel(const int* __restrict__ topk_e, const float* __restrict__ topk_w,
                              int* __restrict__ cnt, int* __restrict__ ltok, float* __restrict__ lw) {
  const int t = blockIdx.x * blockDim.x + threadIdx.x;
  if (t >= TTOK) return;
#pragma unroll
  for (int j = 0; j < 2; ++j) {
    int e = topk_e[2 * t + j];
    int s = atomicAdd(&cnt[e], 1);
    ltok[e * TTOK + s] = t;
    lw[e * TTOK + s] = topk_w[2 * t + j];
  }
}

__global__ void prefix_kernel(const int* __restrict__ cnt, int* __restrict__ base) {
  if (threadIdx.x == 0 && blockIdx.x == 0) {
    int b = 0;
    for (int e = 0; e < NE; ++e) { base[e] = b; b += cnt[e]; }
  }
}

// ============ 256x256 8-phase GEMM kernels (T2+T3+T4+T5 template) ============
// LDS: 2 dbuf x (A,B) x 256 rows x 64 cols bf16 = 128 KiB. 8 waves (2M x 4N).
// Swizzle: phys 16B-slot = logical_slot ^ (row & 7) within each 128B row,
// applied on the global source of global_load_lds AND on ds_read addresses.

#define MFMA(a, b, c) __builtin_amdgcn_mfma_f32_16x16x32_bf16((a), (b), (c), 0, 0, 0)

// stage half-tile: role h of A (or B), K-tile kt, into buf kt&1
#define STAGE_A(h, kt) do { int _b = ((kt) & 1) * 32768; size_t _k = (size_t)(kt) * 128; \
    glds16(bA + oA[(h)*2 + 0] + _k, ldsA + _b + (h) * 16384 + d0); \
    glds16(bA + oA[(h)*2 + 1] + _k, ldsA + _b + (h) * 16384 + d1); } while (0)
#define STAGE_B(h, kt) do { int _b = ((kt) & 1) * 32768; size_t _k = (size_t)(kt) * 128; \
    glds16(bB + oB[(h)*2 + 0] + _k, ldsB + _b + (h) * 16384 + d0); \
    glds16(bB + oB[(h)*2 + 1] + _k, ldsB + _b + (h) * 16384 + d1); } while (0)

#define RD_A(mf, ks) (*(const bf16x8*)(ldsA + curb + arow + (mf) * (16 * 128) + ((ks) ? kcol1 : kcol0)))
#define RD_B(nf, ks) (*(const bf16x8*)(ldsB + curb + brow + (nf) * (16 * 128) + ((ks) ? kcol1 : kcol0)))

#define BAR()   __builtin_amdgcn_s_barrier()
#define LGKM0() do { asm volatile("s_waitcnt lgkmcnt(0)" ::: "memory"); \
                     __builtin_amdgcn_sched_barrier(0); } while (0)

// ---------------- pass1: h = silu(x w1^T) * (x w3^T) ----------------
// B-tile rows interleave w1/w3 at 16-row granularity: row br -> (br>>4)&1 ? w3 : w1,
// w-row = tn*128 + ((br>>5)<<4) + (br&15). So frag nf pairs: (0,1)=(g,u) same col,
// (2,3)=(g,u) col+16 -> thread-local silu combine.
__launch_bounds__(512, 2)
__global__ void pass1_kernel(const bf16* __restrict__ xb, const bf16* __restrict__ w1b,
                             bf16* __restrict__ hbuf, const int* __restrict__ cnt,
                             const int* __restrict__ basep, const int* __restrict__ ltok) {
  const int e = blockIdx.z;
  const int c = cnt[e];
  const int tm = blockIdx.y;
  if (tm * 256 >= c) return;
  const int tn = blockIdx.x;

  __shared__ __align__(16) bf16 sA[2][256 * 64];
  __shared__ __align__(16) bf16 sB[2][256 * 64];
  char* const ldsA = (char*)&sA[0][0];
  char* const ldsB = (char*)&sB[0][0];

  const int tid = threadIdx.x;
  const int r0 = tid >> 3;                  // 0..63
  const int ls = (tid & 7) ^ (r0 & 7);      // pre-swizzled slot-in-row
  const int d0 = tid * 16, d1 = (tid + 512) * 16;
  const char* const bA = (const char*)xb;
  const char* const bB = (const char*)w1b;  // w3b is contiguous after w1b

  uint32_t oA[4], oB[4];
#pragma unroll
  for (int i = 0; i < 4; ++i) {
    int trow = i * 64 + r0;
    int slot = tm * 256 + trow; if (slot >= c) slot = c - 1;
    oA[i] = (uint32_t)((size_t)ltok[e * TTOK + slot] * (HID * 2) + ls * 16);
    int br = i * 64 + r0;
    int w = (br >> 4) & 1;
    int wr = tn * 128 + ((br >> 5) << 4) + (br & 15);
    size_t off = ((size_t)e * INTER + wr) * (HID * 2) + (size_t)ls * 16;
    if (w) off += (size_t)NE * INTER * HID * 2;
    oB[i] = (uint32_t)off;
  }

  const int lane = tid & 63, wid = tid >> 6;
  const int wm = wid >> 2, wn = wid & 3;    // 2 x 4 waves
  const int ln15 = lane & 15, kq = lane >> 4;
  const int swz = (ln15 & 7) << 4;
  const int kcol0 = (kq * 16) ^ swz;
  const int kcol1 = (64 + kq * 16) ^ swz;
  const int arow = (wm * 128 + ln15) * 128;
  const int brow = (wn * 64 + ln15) * 128;

  f32x4 acc[8][4];
#pragma unroll
  for (int m = 0; m < 8; ++m)
#pragma unroll
    for (int n = 0; n < 4; ++n) acc[m][n] = (f32x4){0.f, 0.f, 0.f, 0.f};

  // prologue: tile0 fully + A0,A1,B0 of tile1
  STAGE_A(0, 0); STAGE_A(1, 0); STAGE_B(0, 0); STAGE_B(1, 0);
  asm volatile("s_waitcnt vmcnt(4)" ::: "memory");
  STAGE_A(0, 1); STAGE_A(1, 1); STAGE_B(0, 1);
  asm volatile("s_waitcnt vmcnt(6)" ::: "memory");
  BAR();

  bf16x8 a0[4][2], a1[4][2], b0[2][2], b1[2][2];
  int cur = 0;
  for (int t = 0; t < NT1; ++t, cur ^= 1) {
    const int curb = cur * 32768;
    // ---- phase 1: read A-mhalf0 + B-nhalf0, stage B1(t+1), MFMA Q00 ----
#pragma unroll
    for (int m = 0; m < 4; ++m) { a0[m][0] = RD_A(m, 0); a0[m][1] = RD_A(m, 1); }
#pragma unroll
    for (int n = 0; n < 2; ++n) { b0[n][0] = RD_B(n, 0); b0[n][1] = RD_B(n, 1); }
    if (t + 1 < NT1) STAGE_B(1, t + 1);
    BAR(); LGKM0();
    __builtin_amdgcn_s_setprio(1);
#pragma unroll
    for (int m = 0; m < 4; ++m)
#pragma unroll
      for (int n = 0; n < 2; ++n) {
        acc[m][n] = MFMA(a0[m][0], b0[n][0], acc[m][n]);
        acc[m][n] = MFMA(a0[m][1], b0[n][1], acc[m][n]);
      }
    __builtin_amdgcn_s_setprio(0);
    BAR();
    // ---- phase 2: read A-mhalf1, stage A0(t+2), MFMA Q10 ----
#pragma unroll
    for (int m = 0; m < 4; ++m) { a1[m][0] = RD_A(4 + m, 0); a1[m][1] = RD_A(4 + m, 1); }
    if (t + 2 < NT1) STAGE_A(0, t + 2);
    BAR(); LGKM0();
    __builtin_amdgcn_s_setprio(1);
#pragma unroll
    for (int m = 0; m < 4; ++m)
#pragma unroll
      for (int n = 0; n < 2; ++n) {
        acc[4 + m][n] = MFMA(a1[m][0], b0[n][0], acc[4 + m][n]);
        acc[4 + m][n] = MFMA(a1[m][1], b0[n][1], acc[4 + m][n]);
      }
    __builtin_amdgcn_s_setprio(0);
    BAR();
    // ---- phase 3: read B-nhalf1, stage A1(t+2), MFMA Q01 ----
#pragma unroll
    for (int n = 0; n < 2; ++n) { b1[n][0] = RD_B(2 + n, 0); b1[n][1] = RD_B(2 + n, 1); }
    if (t + 2 < NT1) STAGE_A(1, t + 2);
    BAR(); LGKM0();
    __builtin_amdgcn_s_setprio(1);
#pragma unroll
    for (int m = 0; m < 4; ++m)
#pragma unroll
      for (int n = 0; n < 2; ++n) {
        acc[m][2 + n] = MFMA(a0[m][0], b1[n][0], acc[m][2 + n]);
        acc[m][2 + n] = MFMA(a0[m][1], b1[n][1], acc[m][2 + n]);
      }
    __builtin_amdgcn_s_setprio(0);
    BAR();
    // ---- phase 4: stage B0(t+2), MFMA Q11, counted vmcnt ----
    if (t + 2 < NT1) STAGE_B(0, t + 2);
    __builtin_amdgcn_s_setprio(1);
#pragma unroll
    for (int m = 0; m < 4; ++m)
#pragma unroll
      for (int n = 0; n < 2; ++n) {
        acc[4 + m][2 + n] = MFMA(a1[m][0], b1[n][0], acc[4 + m][2 + n]);
        acc[4 + m][2 + n] = MFMA(a1[m][1], b1[n][1], acc[4 + m][2 + n]);
      }
    __builtin_amdgcn_s_setprio(0);
    if (t + 2 < NT1) asm volatile("s_waitcnt vmcnt(6)" ::: "memory");
    else             asm volatile("s_waitcnt vmcnt(0)" ::: "memory");
    BAR();
  }

  // epilogue: silu(g)*u, thread-local pairs (nf0,nf1) and (nf2,nf3)
  const int be = basep[e];
#pragma unroll
  for (int mh = 0; mh < 2; ++mh)
#pragma unroll
    for (int mf = 0; mf < 4; ++mf)
#pragma unroll
      for (int j = 0; j < 4; ++j) {
        const int slot = tm * 256 + wm * 128 + mh * 64 + mf * 16 + kq * 4 + j;
        if (slot < c) {
          bf16* hrow = hbuf + (size_t)(be + slot) * INTER + tn * 128;
#pragma unroll
          for (int p = 0; p < 2; ++p) {
            const float g = acc[mh * 4 + mf][2 * p][j];
            const float u = acc[mh * 4 + mf][2 * p + 1][j];
            const float hv = g / (1.f + __expf(-g)) * u;
            hrow[wn * 32 + p * 16 + ln15] = (bf16)hv;
          }
        }
      }
}

// ---------------- pass2: out[t,:] += w * (h w2^T) ----------------
__launch_bounds__(512, 2)
__global__ void pass2_kernel(const bf16* __restrict__ hbuf, const bf16* __restrict__ w2b,
                             float* __restrict__ out, const int* __restrict__ cnt,
                             const int* __restrict__ basep, const int* __restrict__ ltok,
                             const float* __restrict__ lw) {
  const int e = blockIdx.z;
  const int c = cnt[e];
  const int tm = blockIdx.y;
  if (tm * 256 >= c) return;
  const int tn = blockIdx.x;

  __shared__ __align__(16) bf16 sA[2][256 * 64];
  __shared__ __align__(16) bf16 sB[2][256 * 64];
  char* const ldsA = (char*)&sA[0][0];
  char* const ldsB = (char*)&sB[0][0];

  const int tid = threadIdx.x;
  const int r0 = tid >> 3;
  const int ls = (tid & 7) ^ (r0 & 7);
  const int d0 = tid * 16, d1 = (tid + 512) * 16;
  const int be = basep[e];
  const char* const bA = (const char*)hbuf;
  const char* const bB = (const char*)w2b;

  uint32_t oA[4], oB[4];
#pragma unroll
  for (int i = 0; i < 4; ++i) {
    int trow = i * 64 + r0;
    int slot = tm * 256 + trow; if (slot >= c) slot = c - 1;
    oA[i] = (uint32_t)((size_t)(be + slot) * (INTER * 2) + ls * 16);
    int br = i * 64 + r0;
    oB[i] = (uint32_t)(((size_t)e * HID + tn * 256 + br) * (INTER * 2) + (size_t)ls * 16);
  }

  const int lane = tid & 63, wid = tid >> 6;
  const int wm = wid >> 2, wn = wid & 3;
  const int ln15 = lane & 15, kq = lane >> 4;
  const int swz = (ln15 & 7) << 4;
  const int kcol0 = (kq * 16) ^ swz;
  const int kcol1 = (64 + kq * 16) ^ swz;
  const int arow = (wm * 128 + ln15) * 128;
  const int brow = (wn * 64 + ln15) * 128;

  f32x4 acc[8][4];
#pragma unroll
  for (int m = 0; m < 8; ++m)
#pragma unroll
    for (int n = 0; n < 4; ++n) acc[m][n] = (f32x4){0.f, 0.f, 0.f, 0.f};

  STAGE_A(0, 0); STAGE_A(1, 0); STAGE_B(0, 0); STAGE_B(1, 0);
  asm volatile("s_waitcnt vmcnt(4)" ::: "memory");
  STAGE_A(0, 1); STAGE_A(1, 1); STAGE_B(0, 1);
  asm volatile("s_waitcnt vmcnt(6)" ::: "memory");
  BAR();

  bf16x8 a0[4][2], a1[4][2], b0[2][2], b1[2][2];
  int cur = 0;
  for (int t = 0; t < NT2; ++t, cur ^= 1) {
    const int curb = cur * 32768;
#pragma unroll
    for (int m = 0; m < 4; ++m) { a0[m][0] = RD_A(m, 0); a0[m][1] = RD_A(m, 1); }
#pragma unroll
    for (int n = 0; n < 2; ++n) { b0[n][0] = RD_B(n, 0); b0[n][1] = RD_B(n, 1); }
    if (t + 1 < NT2) STAGE_B(1, t + 1);
    BAR(); LGKM0();
    __builtin_amdgcn_s_setprio(1);
#pragma unroll
    for (int m = 0; m < 4; ++m)
#pragma unroll
      for (int n = 0; n < 2; ++n) {
        acc[m][n] = MFMA(a0[m][0], b0[n][0], acc[m][n]);
        acc[m][n] = MFMA(a0[m][1], b0[n][1], acc[m][n]);
      }
    __builtin_amdgcn_s_setprio(0);
    BAR();
#pragma unroll
    for (int m = 0; m < 4; ++m) { a1[m][0] = RD_A(4 + m, 0); a1[m][1] = RD_A(4 + m, 1); }
    if (t + 2 < NT2) STAGE_A(0, t + 2);
    BAR(); LGKM0();
    __builtin_amdgcn_s_setprio(1);
#pragma unroll
    for (int m = 0; m < 4; ++m)
#pragma unroll
      for (int n = 0; n < 2; ++n) {
        acc[4 + m][n] = MFMA(a1[m][0], b0[n][0], acc[4 + m][n]);
        acc[4 + m][n] = MFMA(a1[m][1], b0[n][1], acc[4 + m][n]);
      }
    __builtin_amdgcn_s_setprio(0);
    BAR();
#pragma unroll
    for (int n = 0; n < 2; ++n) { b1[n][0] = RD_B(2 + n, 0); b1[n][1] = RD_B(2 + n, 1); }
    if (t + 2 < NT2) STAGE_A(1, t + 2);
    BAR(); LGKM0();
    __builtin_amdgcn_s_setprio(1);
#pragma unroll
    for (int m = 0; m < 4; ++m)
#pragma unroll
      for (int n = 0; n < 2; ++n) {
        acc[m][2 + n] = MFMA(a0[m][0], b1[n][0], acc[m][2 + n]);
        acc[m][2 + n] = MFMA(a0[m][1], b1[n][1], acc[m][2 + n]);
      }
    __builtin_amdgcn_s_setprio(0);
    BAR();
    if (t + 2 < NT2) STAGE_B(0, t + 2);
    __builtin_amdgcn_s_setprio(1);
#pragma unroll
    for (int m = 0; m < 4; ++m)
#pragma unroll
      for (int n = 0; n < 2; ++n) {
        acc[4 + m][2 + n] = MFMA(a1[m][0], b1[n][0], acc[4 + m][2 + n]);
        acc[4 + m][2 + n] = MFMA(a1[m][1], b1[n][1], acc[4 + m][2 + n]);
      }
    __builtin_amdgcn_s_setprio(0);
    if (t + 2 < NT2) asm volatile("s_waitcnt vmcnt(6)" ::: "memory");
    else             asm volatile("s_waitcnt vmcnt(0)" ::: "memory");
    BAR();
  }

#pragma unroll
  for (int mh = 0; mh < 2; ++mh)
#pragma unroll
    for (int mf = 0; mf < 4; ++mf)
#pragma unroll
      for (int j = 0; j < 4; ++j) {
        const int slot = tm * 256 + wm * 128 + mh * 64 + mf * 16 + kq * 4 + j;
        if (slot < c) {
          const int tok = ltok[e * TTOK + slot];
          const float wt = lw[e * TTOK + slot];
          float* orow = out + (size_t)tok * HID + tn * 256;
#pragma unroll
          for (int n = 0; n < 4; ++n)
            atomicAdd(orow + wn * 64 + n * 16 + ln15, wt * acc[mh * 4 + mf][n][j]);
        }
      }
}

extern "C" void kernel_launch(void* const* d_in, const int* in_sizes, int n_in,
                              void* d_out, int out_size, void* d_ws, size_t ws_size,
                              hipStream_t stream) {
  const float* x  = (const float*)d_in[0];
  const float* gw = (const float*)d_in[1];
  const float* w1 = (const float*)d_in[2];
  const float* w3 = (const float*)d_in[3];
  const float* w2 = (const float*)d_in[4];
  float* out = (float*)d_out;

  char* ws = (char*)d_ws;
  size_t off = 0;
  auto take = [&](size_t bytes) -> char* {
    char* p = ws + off;
    off += (bytes + 255) & ~(size_t)255;
    return p;
  };
  bf16* xb    = (bf16*)take((size_t)TTOK * HID * 2);
  bf16* w1b   = (bf16*)take((size_t)NE * INTER * HID * 2);   // w3b MUST follow contiguously
  bf16* w3b   = (bf16*)take((size_t)NE * INTER * HID * 2);
  bf16* w2b   = (bf16*)take((size_t)NE * HID * INTER * 2);
  bf16* hbuf  = (bf16*)take((size_t)TTOK * 2 * INTER * 2);
  int*   topk_e = (int*)take(TTOK * 2 * 4);
  float* topk_w = (float*)take(TTOK * 2 * 4);
  int*   ltok   = (int*)take(NE * TTOK * 4);
  float* lwgt   = (float*)take(NE * TTOK * 4);
  int*   cntp   = (int*)take(64);
  int*   basep  = (int*)take(64);
  if (off > ws_size) return;

  hipMemsetAsync(d_out, 0, (size_t)out_size * 4, stream);
  hipMemsetAsync(cntp, 0, 64, stream);

  cvt_f32_bf16<<<2048, 256, 0, stream>>>(x,  xb,  (long)TTOK * HID);
  cvt_f32_bf16<<<4096, 256, 0, stream>>>(w1, w1b, (long)NE * INTER * HID);
  cvt_f32_bf16<<<4096, 256, 0, stream>>>(w3, w3b, (long)NE * INTER * HID);
  cvt_f32_bf16<<<4096, 256, 0, stream>>>(w2, w2b, (long)NE * HID * INTER);

  router_kernel<<<TTOK / 4, 256, 0, stream>>>(x, gw, topk_e, topk_w);
  gather_kernel<<<TTOK / 256, 256, 0, stream>>>(topk_e, topk_w, cntp, ltok, lwgt);
  prefix_kernel<<<1, 64, 0, stream>>>(cntp, basep);

  pass1_kernel<<<dim3(INTER / 128, TTOK / 256, NE), 512, 0, stream>>>(
      xb, w1b, hbuf, cntp, basep, ltok);
  pass2_kernel<<<dim3(HID / 256, TTOK / 256, NE), 512, 0, stream>>>(
      hbuf, w2b, out, cntp, basep, ltok, lwgt);
}